// Round 10
// baseline (27331.573 us; speedup 1.0000x reference)
//
#include <hip/hip_runtime.h>
#include <hip/hip_bf16.h>
#include <math.h>

// Problem constants: V=32000, D=256, H=256, L=2, C=2, B=64, T=1024, PAD=0
namespace {
constexpr int Bn = 64;
constexpr int Tn = 1024;
constexpr int Dn = 256;
constexpr int Hn = 256;
}

typedef __attribute__((ext_vector_type(8))) short short8;
typedef __attribute__((ext_vector_type(4))) float f32x4;

template <typename T>
__device__ __forceinline__ float ldf(const T* p, long i);
template <>
__device__ __forceinline__ float ldf<float>(const float* p, long i) { return p[i]; }
template <>
__device__ __forceinline__ float ldf<__hip_bfloat16>(const __hip_bfloat16* p, long i) {
  return __bfloat162float(p[i]);
}

__device__ __forceinline__ float sigmf(float x) { return 1.0f / (1.0f + __expf(-x)); }
__device__ __forceinline__ float tanh_fast(float x) {
  return 1.0f - 2.0f / (__expf(2.0f * x) + 1.0f);
}

// ---------------------------------------------------------------------------
// Dtype detector (validated round 2: flag=1 -> f32 inputs).
// ---------------------------------------------------------------------------
__global__ void k_detect(const unsigned short* __restrict__ e, int* __restrict__ flag) {
  __shared__ int sbuf[256];
  int bad = 0;
  for (int i = threadIdx.x; i < 4096; i += 256) {
    const unsigned short v = e[i];
    const int ex = (v >> 7) & 0xFF;
    bad += (ex >= 137) ? 1 : 0;
  }
  sbuf[threadIdx.x] = bad;
  __syncthreads();
  for (int s = 128; s > 0; s >>= 1) {
    if (threadIdx.x < s) sbuf[threadIdx.x] += sbuf[threadIdx.x + s];
    __syncthreads();
  }
  if (threadIdx.x == 0) flag[0] = (sbuf[0] > 64) ? 1 : 0;
}

__global__ void k_lengths(const int* __restrict__ x, int* __restrict__ len) {
  const int b = blockIdx.x;
  int cnt = 0;
  for (int t = threadIdx.x; t < Tn; t += blockDim.x) cnt += (x[b * Tn + t] != 0) ? 1 : 0;
  __shared__ int sbuf[256];
  sbuf[threadIdx.x] = cnt;
  __syncthreads();
  for (int s = 128; s > 0; s >>= 1) {
    if (threadIdx.x < s) sbuf[threadIdx.x] += sbuf[threadIdx.x + s];
    __syncthreads();
  }
  if (threadIdx.x == 0) len[b] = sbuf[0];
}

// ===========================================================================
// FAST PATH
// ===========================================================================

// biases -> f32 [4][1024] (order: f0,b0,f1,b1).
__global__ void k_prep_small(const void* b0f, const void* b0b, const void* b1f, const void* b1b,
                             const int* __restrict__ flag, float* __restrict__ biasbuf) {
  const int tid = threadIdx.x;
  const bool isf32 = flag[0] != 0;
  for (int idx = tid; idx < 4096; idx += 256) {
    const int j = idx >> 10, col = idx & 1023;
    const void* src = (j == 0) ? b0f : (j == 1) ? b0b : (j == 2) ? b1f : b1b;
    biasbuf[idx] = isf32 ? ((const float*)src)[col]
                         : __bfloat162float(((const __hip_bfloat16*)src)[col]);
  }
}

// Transpose+convert W[(H+XK) x 1024] -> WhT bf16 [1024][256], WxT bf16 [1024][XK].
__global__ void k_prepw(const void* W0, const void* W1, const void* W2, const void* W3,
                        const int* __restrict__ flag, __hip_bfloat16* __restrict__ whT,
                        __hip_bfloat16* __restrict__ wxT0, __hip_bfloat16* __restrict__ wxT1) {
  const int j = blockIdx.z;
  const int rows = (j < 2) ? 512 : 768;
  const int bx = blockIdx.x;
  if (bx * 64 >= rows) return;
  const int by = blockIdx.y;
  const void* W = (j == 0) ? W0 : (j == 1) ? W1 : (j == 2) ? W2 : W3;
  const bool isf32 = flag[0] != 0;
  __shared__ float tile[64][65];
  const int tid = threadIdx.x;
  const int c = tid & 63, r4 = tid >> 6;
#pragma unroll
  for (int rep = 0; rep < 16; ++rep) {
    const int rr = r4 * 16 + rep;
    const size_t idx = (size_t)(bx * 64 + rr) * 1024 + by * 64 + c;
    tile[rr][c] = isf32 ? ((const float*)W)[idx]
                        : __bfloat162float(((const __hip_bfloat16*)W)[idx]);
  }
  __syncthreads();
  const int kk = tid & 63;
#pragma unroll
  for (int rep = 0; rep < 16; ++rep) {
    const int a = r4 * 16 + rep;
    const int n = by * 64 + a;
    const int k = bx * 64 + kk;
    const __hip_bfloat16 v = __float2bfloat16(tile[kk][a]);
    if (k < 256) {
      whT[(size_t)j * (1024 * 256) + (size_t)n * 256 + k] = v;
    } else {
      const int k2 = k - 256;
      if (j < 2)
        wxT0[(size_t)j * (1024 * 256) + (size_t)n * 256 + k2] = v;
      else
        wxT1[(size_t)(j - 2) * (1024 * 512) + (size_t)n * 512 + k2] = v;
    }
  }
}

// ---------------------------------------------------------------------------
// One-shot embedding gather -> xemb[t][b][256] bf16 (direction-independent;
// both directions read the same ascending-t rows at different offsets).
// ---------------------------------------------------------------------------
__global__ void k_gather_all(const int* __restrict__ x, const void* __restrict__ E,
                             const int* __restrict__ flag, __hip_bfloat16* __restrict__ xemb) {
  const int t = blockIdx.x, tid = threadIdx.x;
  __hip_bfloat16* __restrict__ dst = xemb + (size_t)t * 64 * 256;
  const bool isf32 = flag[0] != 0;
  for (int b = 0; b < 64; ++b) {
    const int tok = x[b * Tn + t];
    const float v = isf32 ? ((const float*)E)[(size_t)tok * Dn + tid]
                          : __bfloat162float(((const __hip_bfloat16*)E)[(size_t)tok * Dn + tid]);
    dst[b * 256 + tid] = __float2bfloat16(v);
  }
}

// ---------------------------------------------------------------------------
// xproj GEMM tile worker (128x128 tile, B staged in LDS, K-chunks of 256).
// smem must be >= 128*264 shorts. Processes tiles [gIdx, ntiles) stride nBlk.
// out[d][Mrows][1024] f32 = A_d[Mrows][K] @ WT_d^T + bias_d.
// ---------------------------------------------------------------------------
template <int K>
__device__ __forceinline__ void gemm_tiles(short* smem, const int nBlk, const int gIdx,
                                           const __hip_bfloat16* __restrict__ Af,
                                           const __hip_bfloat16* __restrict__ Ab,
                                           const __hip_bfloat16* __restrict__ WT,
                                           const float* __restrict__ bias,
                                           float* __restrict__ out, const int Mrows) {
  constexpr int KC = 256;
  __hip_bfloat16(*Btile)[KC + 8] = (__hip_bfloat16(*)[KC + 8])smem;
  const int tid = threadIdx.x, w = tid >> 6, L = tid & 63, quad = L >> 4, l16 = L & 15;
  const int mtiles = Mrows >> 7;
  const int ntiles = mtiles * 8 * 2;
  bool first = true;
  for (int tix = gIdx; tix < ntiles; tix += nBlk) {
    const int bx = tix % mtiles;
    const int rem = tix / mtiles;
    const int by = rem & 7;
    const int dz = rem >> 3;
    const __hip_bfloat16* __restrict__ A = dz ? Ab : Af;
    const __hip_bfloat16* __restrict__ WTd = WT + (size_t)dz * (1024 * K);
    float* __restrict__ o = out + (size_t)dz * Mrows * 1024;

    f32x4 acc[2][8];
#pragma unroll
    for (int nt = 0; nt < 8; ++nt) {
      const float bv = bias[dz * 1024 + by * 128 + nt * 16 + l16];
#pragma unroll
      for (int mt = 0; mt < 2; ++mt) {
        acc[mt][nt][0] = bv; acc[mt][nt][1] = bv; acc[mt][nt][2] = bv; acc[mt][nt][3] = bv;
      }
    }
    const __hip_bfloat16* __restrict__ arow0 = A + (size_t)(bx * 128 + w * 32 + l16) * K;

    for (int ch = 0; ch < K / KC; ++ch) {
      if (!first) __syncthreads();
      first = false;
#pragma unroll
      for (int it = 0; it < 16; ++it) {
        const int idx = it * 256 + tid;
        const int col = idx >> 5, seg = idx & 31;
        *(short8*)&Btile[col][seg * 8] =
            *(const short8*)(WTd + (size_t)(by * 128 + col) * K + ch * KC + seg * 8);
      }
      __syncthreads();
#pragma unroll
      for (int kc = 0; kc < 8; ++kc) {
        const short8 a0 = *(const short8*)(arow0 + ch * KC + kc * 32 + quad * 8);
        const short8 a1 = *(const short8*)(arow0 + 16 * K + ch * KC + kc * 32 + quad * 8);
#pragma unroll
        for (int nt = 0; nt < 8; ++nt) {
          const short8 b = *(const short8*)&Btile[nt * 16 + l16][kc * 32 + quad * 8];
          acc[0][nt] = __builtin_amdgcn_mfma_f32_16x16x32_bf16(a0, b, acc[0][nt], 0, 0, 0);
          acc[1][nt] = __builtin_amdgcn_mfma_f32_16x16x32_bf16(a1, b, acc[1][nt], 0, 0, 0);
        }
      }
    }
#pragma unroll
    for (int mt = 0; mt < 2; ++mt)
#pragma unroll
      for (int nt = 0; nt < 8; ++nt)
#pragma unroll
        for (int r = 0; r < 4; ++r)
          o[(size_t)(bx * 128 + w * 32 + mt * 16 + quad * 4 + r) * 1024 + by * 128 + nt * 16 +
            l16] = acc[mt][nt][r];
  }
}

// Standalone xproj (prologue only): grid (Mrows/128, 8, 2).
template <int K>
__launch_bounds__(256, 2)
__global__ void k_xproj2(const __hip_bfloat16* __restrict__ Af,
                         const __hip_bfloat16* __restrict__ Ab,
                         const __hip_bfloat16* __restrict__ WT, const float* __restrict__ bias,
                         float* __restrict__ xp, const int Mrows) {
  __shared__ short smem[128 * 264];
  const int mtiles = Mrows >> 7;
  const int tix = blockIdx.x + mtiles * (blockIdx.y + 8 * blockIdx.z);
  gemm_tiles<K>(smem, mtiles * 16, tix, Af, Ab, WT, bias, xp, Mrows);
}

// ---------------------------------------------------------------------------
// FUSED dispatch: blocks 0..7 = recurrent phase (tagged-payload sync, r8/r9
// validated); blocks 8.. = xproj GEMM tiles for a future, data-ready job.
// Kernel-boundary barriers provide all cross-job ordering; a slow GEMM only
// extends the dispatch to max(lstm, gemm). s_setprio biases lstm waves.
// ---------------------------------------------------------------------------
template <bool WRITE_SEQ>
__launch_bounds__(256, 2) __global__
void k_fused(const __hip_bfloat16* __restrict__ WhT,  // [2][1024][256] this layer
             const float* __restrict__ xproj,          // [2][Tc][64][1024] f32 (this phase slot)
             const int* __restrict__ lengths,
             unsigned* __restrict__ hgs,  // [2 d][2 par][4 q][64 b][64 u] u32
             float* __restrict__ cstate, float* __restrict__ hstate,  // [2][64][256]
             __hip_bfloat16* __restrict__ seq0,        // [T][64][512] (L0 only)
             const int s0, const int Tc,
             // GEMM job (gk: 0=none, 256=L0, 512=L1):
             const int gk, const __hip_bfloat16* __restrict__ gAf,
             const __hip_bfloat16* __restrict__ gAb, const __hip_bfloat16* __restrict__ gWT,
             const float* __restrict__ gbias, float* __restrict__ gout, const int gMrows) {
  __shared__ short smem[128 * 264];  // GEMM Btile; lstm uses first 64*272 shorts

  if (blockIdx.x >= 8) {
    asm volatile("s_setprio 0");
    if (gk == 256)
      gemm_tiles<256>(smem, (int)gridDim.x - 8, (int)blockIdx.x - 8, gAf, gAb, gWT, gbias, gout,
                      gMrows);
    else if (gk == 512)
      gemm_tiles<512>(smem, (int)gridDim.x - 8, (int)blockIdx.x - 8, gAf, gAb, gWT, gbias, gout,
                      gMrows);
    return;
  }
  asm volatile("s_setprio 3");

  __hip_bfloat16(*h_lds)[272] = (__hip_bfloat16(*)[272])smem;
  const int d = blockIdx.x >> 2;
  const int q = blockIdx.x & 3;
  const int tid = threadIdx.x;
  const int w = tid >> 6, L = tid & 63, quad = L >> 4, l16 = L & 15;
  const int u = q * 64 + w * 16 + l16;

  for (int idx = tid; idx < 64 * 272; idx += 256) (&h_lds[0][0])[idx] = __float2bfloat16(0.0f);

  const __hip_bfloat16* __restrict__ Wd = WhT + (size_t)d * (1024 * 256);
  short8 wfrag[4][8];
#pragma unroll
  for (int g = 0; g < 4; ++g)
#pragma unroll
    for (int kc = 0; kc < 8; ++kc)
      wfrag[g][kc] = *(const short8*)(Wd + (size_t)(g * 256 + u) * 256 + kc * 32 + quad * 8);

  float c_reg[16], h_reg[16];
  int len_b[16];
#pragma unroll
  for (int mt = 0; mt < 4; ++mt)
#pragma unroll
    for (int r = 0; r < 4; ++r) {
      const int idx = mt * 4 + r;
      const int b = mt * 16 + quad * 4 + r;
      len_b[idx] = lengths[b];
      if (s0 == 0) {
        c_reg[idx] = 0.0f;
        h_reg[idx] = 0.0f;
      } else {
        c_reg[idx] = cstate[((size_t)(d * 64 + b) << 8) + u];
        h_reg[idx] = hstate[((size_t)(d * 64 + b) << 8) + u];
      }
    }
  __syncthreads();
#pragma unroll
  for (int mt = 0; mt < 4; ++mt)
#pragma unroll
    for (int r = 0; r < 4; ++r)
      h_lds[mt * 16 + quad * 4 + r][u] = __float2bfloat16(h_reg[mt * 4 + r]);
  __syncthreads();

  for (int sl = 0; sl < Tc; ++sl) {
    const int s = s0 + sl;
    const int t = d ? (Tn - 1 - s) : s;
    const int tl = d ? (Tc - 1 - sl) : sl;

    // 1. C-init from xproj
    f32x4 acc[4][4];
#pragma unroll
    for (int mt = 0; mt < 4; ++mt) {
      const float* __restrict__ xrow =
          xproj + ((size_t)(d * Tc + tl) * 64 + mt * 16 + quad * 4) * 1024 + u;
#pragma unroll
      for (int g = 0; g < 4; ++g)
#pragma unroll
        for (int r = 0; r < 4; ++r) acc[mt][g][r] = xrow[(size_t)r * 1024 + g * 256];
    }

    // 2. tagged-payload exchange (single RT in the common case)
    if (s > 0) {
      if (w != q) {
        const unsigned long long* __restrict__ src64 =
            (const unsigned long long*)(hgs + ((((size_t)d * 2 + ((s - 1) & 1)) * 4 + w) << 12));
        const unsigned exp = (unsigned)s;
        unsigned long long v[32];
        unsigned pend = 0xFFFFFFFFu;
        int tries = 0;
        do {
          if (tries++) __builtin_amdgcn_s_sleep(1);
#pragma unroll
          for (int i = 0; i < 32; ++i)
            if (pend & (1u << i))
              v[i] = __hip_atomic_load(src64 + i * 64 + L, __ATOMIC_RELAXED,
                                       __HIP_MEMORY_SCOPE_AGENT);
#pragma unroll
          for (int i = 0; i < 32; ++i)
            if (pend & (1u << i)) {
              const unsigned lo = (unsigned)v[i], hi = (unsigned)(v[i] >> 32);
              if ((lo >> 16) == exp && (hi >> 16) == exp) pend &= ~(1u << i);
            }
        } while (pend);
#pragma unroll
        for (int i = 0; i < 32; ++i) {
          const int j = i * 64 + L;
          const unsigned lo = (unsigned)v[i], hi = (unsigned)(v[i] >> 32);
          const unsigned packed = (lo & 0xFFFFu) | (hi << 16);
          *(unsigned*)&h_lds[j >> 5][w * 64 + (j & 31) * 2] = packed;
        }
      }
      __syncthreads();
    }

    // 3. z += h @ Wh
#pragma unroll
    for (int kc = 0; kc < 8; ++kc) {
#pragma unroll
      for (int mt = 0; mt < 4; ++mt) {
        const short8 a = *(const short8*)&h_lds[mt * 16 + l16][kc * 32 + quad * 8];
#pragma unroll
        for (int g = 0; g < 4; ++g)
          acc[mt][g] =
              __builtin_amdgcn_mfma_f32_16x16x32_bf16(a, wfrag[g][kc], acc[mt][g], 0, 0, 0);
      }
    }

    // 4. gates + state update; publish tagged slice (write-through u32)
    unsigned* __restrict__ dst32 = hgs + ((((size_t)d * 2 + (s & 1)) * 4 + q) << 12);
    const unsigned tag = ((unsigned)(s + 1)) << 16;
    __hip_bfloat16 hbf[16];
#pragma unroll
    for (int mt = 0; mt < 4; ++mt)
#pragma unroll
      for (int r = 0; r < 4; ++r) {
        const int idx = mt * 4 + r, b = mt * 16 + quad * 4 + r;
        const float fg = sigmf(acc[mt][0][r]);
        const float ig = sigmf(acc[mt][1][r]);
        const float gg = tanh_fast(acc[mt][2][r]);
        const float og = sigmf(acc[mt][3][r]);
        const float cn = fg * c_reg[idx] + ig * gg;
        const float hn = og * tanh_fast(cn);
        if (t < len_b[idx]) {
          c_reg[idx] = cn;
          h_reg[idx] = hn;
        }
        hbf[idx] = __float2bfloat16(h_reg[idx]);
        __hip_atomic_store(dst32 + b * 64 + w * 16 + l16,
                           tag | (unsigned)*(unsigned short*)&hbf[idx], __ATOMIC_RELAXED,
                           __HIP_MEMORY_SCOPE_AGENT);
      }

    __syncthreads();  // LDS overwrite guard

#pragma unroll
    for (int mt = 0; mt < 4; ++mt)
#pragma unroll
      for (int r = 0; r < 4; ++r)
        h_lds[mt * 16 + quad * 4 + r][u] = hbf[mt * 4 + r];

    if (WRITE_SEQ) {
#pragma unroll
      for (int mt = 0; mt < 4; ++mt)
#pragma unroll
        for (int r = 0; r < 4; ++r) {
          const int b = mt * 16 + quad * 4 + r;
          seq0[((size_t)t * 64 + b) * 512 + d * 256 + u] = hbf[mt * 4 + r];
        }
    }
  }

#pragma unroll
  for (int mt = 0; mt < 4; ++mt)
#pragma unroll
    for (int r = 0; r < 4; ++r) {
      const int idx = mt * 4 + r, b = mt * 16 + quad * 4 + r;
      cstate[((size_t)(d * 64 + b) << 8) + u] = c_reg[idx];
      hstate[((size_t)(d * 64 + b) << 8) + u] = h_reg[idx];
    }
}

// ===========================================================================
// SLOW FALLBACK PATH (round-2 passing version, used when ws is too small)
// ===========================================================================
template <typename TW, int XK, bool WRITE_SEQ>
__device__ __forceinline__ void lstm_body(const int* __restrict__ x, const TW* __restrict__ E,
                                          const __hip_bfloat16* __restrict__ seq_in,
                                          const TW* __restrict__ W, const TW* __restrict__ bias,
                                          const int len, const int b, const int dir,
                                          __hip_bfloat16* __restrict__ seq_out,
                                          float* __restrict__ hfin) {
  const int j = threadIdx.x;
  __shared__ float h[Hn];
  __shared__ float xb[XK];
  float hj = 0.0f, cj = 0.0f;
  h[j] = 0.0f;
  const float bfj = ldf(bias, j);
  const float bij = ldf(bias, Hn + j);
  const float bgj = ldf(bias, 2 * Hn + j);
  const float boj = ldf(bias, 3 * Hn + j);
  __syncthreads();
  for (int s = 0; s < Tn; ++s) {
    const int t = dir ? (Tn - 1 - s) : s;
    const bool active = (t < len);
    if (active) {
      if constexpr (XK == Dn) {
        const int tok = x[b * Tn + t];
        xb[j] = ldf(E, (long)tok * Dn + j);
      } else {
        const long base = ((long)(b * Tn + t)) * (2 * Hn);
        xb[j] = __bfloat162float(seq_in[base + j]);
        xb[j + Hn] = __bfloat162float(seq_in[base + j + Hn]);
      }
      __syncthreads();
      float af = bfj, ai = bij, ag = bgj, ao = boj;
#pragma unroll 4
      for (int k = 0; k < Hn; ++k) {
        const float hk = h[k];
        const long r = (long)k * (4 * Hn);
        af += hk * ldf(W, r + j);
        ai += hk * ldf(W, r + Hn + j);
        ag += hk * ldf(W, r + 2 * Hn + j);
        ao += hk * ldf(W, r + 3 * Hn + j);
      }
#pragma unroll 4
      for (int k = 0; k < XK; ++k) {
        const float xk = xb[k];
        const long r = (long)(Hn + k) * (4 * Hn);
        af += xk * ldf(W, r + j);
        ai += xk * ldf(W, r + Hn + j);
        ag += xk * ldf(W, r + 2 * Hn + j);
        ao += xk * ldf(W, r + 3 * Hn + j);
      }
      const float fg = 1.0f / (1.0f + expf(-af));
      const float ig = 1.0f / (1.0f + expf(-ai));
      const float gg = tanhf(ag);
      const float og = 1.0f / (1.0f + expf(-ao));
      const float cn = fg * cj + ig * gg;
      const float hn = og * tanhf(cn);
      __syncthreads();
      hj = hn;
      cj = cn;
      h[j] = hn;
      __syncthreads();
    }
    if constexpr (WRITE_SEQ) {
      seq_out[((long)(b * Tn + t)) * (2 * Hn) + dir * Hn + j] = __float2bfloat16(hj);
    }
  }
  if constexpr (!WRITE_SEQ) hfin[(dir * Bn + b) * Hn + j] = hj;
}

template <int XK, bool WRITE_SEQ>
__global__ void k_lstm(const int* __restrict__ x, const void* __restrict__ E,
                       const __hip_bfloat16* __restrict__ seq_in, const void* __restrict__ Wf,
                       const void* __restrict__ bf, const void* __restrict__ Wb,
                       const void* __restrict__ bb, const int* __restrict__ lengths,
                       const int* __restrict__ flag, __hip_bfloat16* __restrict__ seq_out,
                       float* __restrict__ hfin) {
  const int b = blockIdx.x & (Bn - 1);
  const int dir = blockIdx.x >> 6;
  const int len = lengths[b];
  const void* W = dir ? Wb : Wf;
  const void* bias = dir ? bb : bf;
  if (flag[0]) {
    lstm_body<float, XK, WRITE_SEQ>(x, (const float*)E, seq_in, (const float*)W,
                                    (const float*)bias, len, b, dir, seq_out, hfin);
  } else {
    lstm_body<__hip_bfloat16, XK, WRITE_SEQ>(x, (const __hip_bfloat16*)E, seq_in,
                                             (const __hip_bfloat16*)W, (const __hip_bfloat16*)bias,
                                             len, b, dir, seq_out, hfin);
  }
}

// ---------------------------------------------------------------------------
template <typename TW>
__device__ __forceinline__ void fc_body(const float* __restrict__ hfin, const TW* __restrict__ Wfc,
                                        const TW* __restrict__ bfc, TW* __restrict__ out) {
  const int idx = threadIdx.x;
  const int b = idx >> 1;
  const int cc = idx & 1;
  float acc = ldf(bfc, cc);
  for (int k = 0; k < Hn; ++k) acc += hfin[(0 * Bn + b) * Hn + k] * ldf(Wfc, k * 2 + cc);
  for (int k = 0; k < Hn; ++k) acc += hfin[(1 * Bn + b) * Hn + k] * ldf(Wfc, (Hn + k) * 2 + cc);
  if constexpr (sizeof(TW) == 2) {
    out[b * 2 + cc] = __float2bfloat16(acc);
  } else {
    out[b * 2 + cc] = acc;
  }
}

__global__ void k_fc(const float* __restrict__ hfin, const void* __restrict__ Wfc,
                     const void* __restrict__ bfc, const int* __restrict__ flag,
                     void* __restrict__ out) {
  if (flag[0]) {
    fc_body<float>(hfin, (const float*)Wfc, (const float*)bfc, (float*)out);
  } else {
    fc_body<__hip_bfloat16>(hfin, (const __hip_bfloat16*)Wfc, (const __hip_bfloat16*)bfc,
                            (__hip_bfloat16*)out);
  }
}

// ---------------------------------------------------------------------------
extern "C" void kernel_launch(void* const* d_in, const int* in_sizes, int n_in,
                              void* d_out, int out_size, void* d_ws, size_t ws_size,
                              hipStream_t stream) {
  const int* x = (const int*)d_in[0];
  const void* E = d_in[1];
  const void* Wf0 = d_in[2];
  const void* bf0 = d_in[3];
  const void* Wb0 = d_in[4];
  const void* bb0 = d_in[5];
  const void* Wf1 = d_in[6];
  const void* bf1 = d_in[7];
  const void* Wb1 = d_in[8];
  const void* bb1 = d_in[9];
  const void* Wfc = d_in[10];
  const void* bfc = d_in[11];

  char* ws = (char*)d_ws;
  int* flag = (int*)ws;             // @0
  int* lengths = (int*)(ws + 256);

  const size_t MB = 1ull << 20;
  const size_t KB = 1024;

  k_detect<<<1, 256, 0, stream>>>((const unsigned short*)E, flag);
  k_lengths<<<Bn, 256, 0, stream>>>(x, lengths);

  // fixed 104 MB (weights/state/seq0/xemb) + 4 xproj slots x Tc*512KB
  int Tc = 0;
  {
    const size_t fixed = 104 * MB;
    const int cands[5] = {256, 128, 64, 32, 16};
    for (int i = 0; i < 5; ++i)
      if (fixed + 4ull * cands[i] * 512 * KB <= ws_size) { Tc = cands[i]; break; }
  }

  if (Tc > 0) {
    float* biasbuf = (float*)(ws + 4096);                    // 16 KB
    __hip_bfloat16* whT = (__hip_bfloat16*)(ws + 1 * MB);    // [4][1024][256] = 2 MB
    __hip_bfloat16* wxT0 = (__hip_bfloat16*)(ws + 3 * MB);   // [2][1024][256] = 1 MB
    __hip_bfloat16* wxT1 = (__hip_bfloat16*)(ws + 4 * MB);   // [2][1024][512] = 2 MB
    unsigned* hgs0 = (unsigned*)(ws + 6 * MB);               // 256 KB
    unsigned* hgs1 = (unsigned*)(ws + 6 * MB + 256 * KB);    // 256 KB
    float* cstate0 = (float*)(ws + 7 * MB);                  // 128 KB
    float* hstate0 = (float*)(ws + 7 * MB + 128 * KB);       // 128 KB
    float* cstate1 = (float*)(ws + 7 * MB + 256 * KB);       // 128 KB
    float* hstate1 = (float*)(ws + 7 * MB + 384 * KB);       // 128 KB
    __hip_bfloat16* seq0 = (__hip_bfloat16*)(ws + 8 * MB);   // [1024][64][512] = 64 MB
    __hip_bfloat16* xemb = (__hip_bfloat16*)(ws + 72 * MB);  // [1024][64][256] = 32 MB
    const size_t slotB = (size_t)Tc * 512 * KB;              // [2][Tc*64][1024] f32
    float* xsl0[2] = {(float*)(ws + 104 * MB), (float*)(ws + 104 * MB + slotB)};
    float* xsl1[2] = {(float*)(ws + 104 * MB + 2 * slotB), (float*)(ws + 104 * MB + 3 * slotB)};

    k_prep_small<<<1, 256, 0, stream>>>(bf0, bb0, bf1, bb1, flag, biasbuf);
    k_prepw<<<dim3(12, 16, 4), 256, 0, stream>>>(Wf0, Wb0, Wf1, Wb1, flag, whT, wxT0, wxT1);
    hipMemsetAsync(hgs0, 0, 512 * KB, stream);  // both mailboxes: kill stale tags
    k_gather_all<<<Tn, 256, 0, stream>>>(x, E, flag, xemb);

    const int P = Tn / Tc;
    const int Mrows = Tc * 64;
    auto t0f = [&](int p) { return p * Tc; };
    auto t0b = [&](int p) { return Tn - p * Tc - Tc; };

    // prologue: L0-xproj(0)
    k_xproj2<256><<<dim3(Mrows / 128, 8, 2), 256, 0, stream>>>(
        xemb + (size_t)t0f(0) * 64 * 256, xemb + (size_t)t0b(0) * 64 * 256, wxT0, biasbuf,
        xsl0[0], Mrows);

    // D phase: L0-lstm(p) + {p<P-1: L0-xproj(p+1) | p==P-1: L1-xproj(0)}
    for (int p = 0; p < P; ++p) {
      int gk;
      const __hip_bfloat16 *gAf, *gAb, *gWT;
      const float* gbias;
      float* gout;
      if (p < P - 1) {
        gk = 256;
        gAf = xemb + (size_t)t0f(p + 1) * 64 * 256;
        gAb = xemb + (size_t)t0b(p + 1) * 64 * 256;
        gWT = wxT0;
        gbias = biasbuf;
        gout = xsl0[(p + 1) & 1];
      } else {
        gk = 512;
        gAf = seq0 + (size_t)t0f(0) * 64 * 512;
        gAb = seq0 + (size_t)t0b(0) * 64 * 512;
        gWT = wxT1;
        gbias = biasbuf + 2048;
        gout = xsl1[0];
      }
      k_fused<true><<<512, 256, 0, stream>>>(whT, xsl0[p & 1], lengths, hgs0, cstate0, hstate0,
                                             seq0, p * Tc, Tc, gk, gAf, gAb, gWT, gbias, gout,
                                             Mrows);
    }
    // E phase: L1-lstm(p) + {p<P-1: L1-xproj(p+1)}
    for (int p = 0; p < P; ++p) {
      int gk = 0;
      const __hip_bfloat16 *gAf = nullptr, *gAb = nullptr, *gWT = nullptr;
      const float* gbias = nullptr;
      float* gout = nullptr;
      if (p < P - 1) {
        gk = 512;
        gAf = seq0 + (size_t)t0f(p + 1) * 64 * 512;
        gAb = seq0 + (size_t)t0b(p + 1) * 64 * 512;
        gWT = wxT1;
        gbias = biasbuf + 2048;
        gout = xsl1[(p + 1) & 1];
      }
      k_fused<false><<<512, 256, 0, stream>>>(whT + 2 * 1024 * 256, xsl1[p & 1], lengths, hgs1,
                                              cstate1, hstate1, nullptr, p * Tc, Tc, gk, gAf, gAb,
                                              gWT, gbias, gout, Mrows);
    }
    k_fc<<<1, 128, 0, stream>>>(hstate1, Wfc, bfc, flag, d_out);
  } else {
    // slow fallback (round-2 passing path)
    __hip_bfloat16* seq0 = (__hip_bfloat16*)(ws + 64 * 1024);
    const size_t seq0_bytes = (size_t)Bn * Tn * 2 * Hn * sizeof(__hip_bfloat16);
    float* hfin = (float*)(ws + 64 * 1024 + seq0_bytes);
    k_lstm<Dn, true><<<2 * Bn, 256, 0, stream>>>(x, E, nullptr, Wf0, bf0, Wb0, bb0, lengths, flag,
                                                 seq0, nullptr);
    k_lstm<2 * Hn, false><<<2 * Bn, 256, 0, stream>>>(x, E, seq0, Wf1, bf1, Wb1, bb1, lengths,
                                                      flag, nullptr, hfin);
    k_fc<<<1, 128, 0, stream>>>(hfin, Wfc, bfc, flag, d_out);
  }
}

// Round 11
// 15221.182 us; speedup vs baseline: 1.7956x; 1.7956x over previous
//
#include <hip/hip_runtime.h>
#include <hip/hip_bf16.h>
#include <math.h>

// Problem constants: V=32000, D=256, H=256, L=2, C=2, B=64, T=1024, PAD=0
namespace {
constexpr int Bn = 64;
constexpr int Tn = 1024;
constexpr int Dn = 256;
constexpr int Hn = 256;
}

typedef __attribute__((ext_vector_type(8))) short short8;
typedef __attribute__((ext_vector_type(4))) float f32x4;

template <typename T>
__device__ __forceinline__ float ldf(const T* p, long i);
template <>
__device__ __forceinline__ float ldf<float>(const float* p, long i) { return p[i]; }
template <>
__device__ __forceinline__ float ldf<__hip_bfloat16>(const __hip_bfloat16* p, long i) {
  return __bfloat162float(p[i]);
}

__device__ __forceinline__ float sigmf(float x) { return 1.0f / (1.0f + __expf(-x)); }
__device__ __forceinline__ float tanh_fast(float x) {
  return 1.0f - 2.0f / (__expf(2.0f * x) + 1.0f);
}

// ---------------------------------------------------------------------------
// Dtype detector (validated round 2: flag=1 -> f32 inputs).
// ---------------------------------------------------------------------------
__global__ void k_detect(const unsigned short* __restrict__ e, int* __restrict__ flag) {
  __shared__ int sbuf[256];
  int bad = 0;
  for (int i = threadIdx.x; i < 4096; i += 256) {
    const unsigned short v = e[i];
    const int ex = (v >> 7) & 0xFF;
    bad += (ex >= 137) ? 1 : 0;
  }
  sbuf[threadIdx.x] = bad;
  __syncthreads();
  for (int s = 128; s > 0; s >>= 1) {
    if (threadIdx.x < s) sbuf[threadIdx.x] += sbuf[threadIdx.x + s];
    __syncthreads();
  }
  if (threadIdx.x == 0) flag[0] = (sbuf[0] > 64) ? 1 : 0;
}

__global__ void k_lengths(const int* __restrict__ x, int* __restrict__ len) {
  const int b = blockIdx.x;
  int cnt = 0;
  for (int t = threadIdx.x; t < Tn; t += blockDim.x) cnt += (x[b * Tn + t] != 0) ? 1 : 0;
  __shared__ int sbuf[256];
  sbuf[threadIdx.x] = cnt;
  __syncthreads();
  for (int s = 128; s > 0; s >>= 1) {
    if (threadIdx.x < s) sbuf[threadIdx.x] += sbuf[threadIdx.x + s];
    __syncthreads();
  }
  if (threadIdx.x == 0) len[b] = sbuf[0];
}

// ===========================================================================
// FAST PATH
// ===========================================================================

// biases -> f32 [4][1024] (order: f0,b0,f1,b1).
__global__ void k_prep_small(const void* b0f, const void* b0b, const void* b1f, const void* b1b,
                             const int* __restrict__ flag, float* __restrict__ biasbuf) {
  const int tid = threadIdx.x;
  const bool isf32 = flag[0] != 0;
  for (int idx = tid; idx < 4096; idx += 256) {
    const int j = idx >> 10, col = idx & 1023;
    const void* src = (j == 0) ? b0f : (j == 1) ? b0b : (j == 2) ? b1f : b1b;
    biasbuf[idx] = isf32 ? ((const float*)src)[col]
                         : __bfloat162float(((const __hip_bfloat16*)src)[col]);
  }
}

// Transpose+convert W[(H+XK) x 1024] -> WhT bf16 [1024][256], WxT bf16 [1024][XK].
__global__ void k_prepw(const void* W0, const void* W1, const void* W2, const void* W3,
                        const int* __restrict__ flag, __hip_bfloat16* __restrict__ whT,
                        __hip_bfloat16* __restrict__ wxT0, __hip_bfloat16* __restrict__ wxT1) {
  const int j = blockIdx.z;
  const int rows = (j < 2) ? 512 : 768;
  const int bx = blockIdx.x;
  if (bx * 64 >= rows) return;
  const int by = blockIdx.y;
  const void* W = (j == 0) ? W0 : (j == 1) ? W1 : (j == 2) ? W2 : W3;
  const bool isf32 = flag[0] != 0;
  __shared__ float tile[64][65];
  const int tid = threadIdx.x;
  const int c = tid & 63, r4 = tid >> 6;
#pragma unroll
  for (int rep = 0; rep < 16; ++rep) {
    const int rr = r4 * 16 + rep;
    const size_t idx = (size_t)(bx * 64 + rr) * 1024 + by * 64 + c;
    tile[rr][c] = isf32 ? ((const float*)W)[idx]
                        : __bfloat162float(((const __hip_bfloat16*)W)[idx]);
  }
  __syncthreads();
  const int kk = tid & 63;
#pragma unroll
  for (int rep = 0; rep < 16; ++rep) {
    const int a = r4 * 16 + rep;
    const int n = by * 64 + a;
    const int k = bx * 64 + kk;
    const __hip_bfloat16 v = __float2bfloat16(tile[kk][a]);
    if (k < 256) {
      whT[(size_t)j * (1024 * 256) + (size_t)n * 256 + k] = v;
    } else {
      const int k2 = k - 256;
      if (j < 2)
        wxT0[(size_t)j * (1024 * 256) + (size_t)n * 256 + k2] = v;
      else
        wxT1[(size_t)(j - 2) * (1024 * 512) + (size_t)n * 512 + k2] = v;
    }
  }
}

// ---------------------------------------------------------------------------
// xproj GEMM v3: 128x128 tile/block, B in LDS, A from global, bf16 output,
// NO bias (lstm adds bias in f32). by-major flat tile order: consecutive
// blocks share the same A 128-row panel (8 by x 2 dz) -> A re-reads hit L2/L3.
// GATHER=true (L0): A rows come from E via token lookup (t = row>>6, b=row&63,
// t offset by t0f/t0b per direction). GATHER=false (L1): A rows from Af/Ab.
// out[dz][row][1024] bf16 = A_dz[row][K] @ WT_dz^T  (row = tl*64 + b).
// ---------------------------------------------------------------------------
template <int K, bool GATHER>
__launch_bounds__(256, 2)
__global__ void k_xproj3(const int* __restrict__ x, const void* __restrict__ E,
                         const int* __restrict__ flag, const __hip_bfloat16* __restrict__ Af,
                         const __hip_bfloat16* __restrict__ Ab,
                         const __hip_bfloat16* __restrict__ WT,  // [2][1024][K]
                         __hip_bfloat16* __restrict__ xp,        // [2][Mrows][1024]
                         const int Mrows, const int t0f, const int t0b) {
  constexpr int KC = 256;
  __shared__ __hip_bfloat16 Btile[128][KC + 8];
  const int tix = blockIdx.x;
  const int by = tix & 7;
  const int dz = (tix >> 3) & 1;
  const int bx = tix >> 4;
  const int tid = threadIdx.x, w = tid >> 6, L = tid & 63, quad = L >> 4, l16 = L & 15;
  const __hip_bfloat16* __restrict__ WTd = WT + (size_t)dz * (1024 * K);
  __hip_bfloat16* __restrict__ o = xp + (size_t)dz * Mrows * 1024;

  f32x4 acc[2][8];
#pragma unroll
  for (int mt = 0; mt < 2; ++mt)
#pragma unroll
    for (int nt = 0; nt < 8; ++nt) {
      acc[mt][nt][0] = 0.f; acc[mt][nt][1] = 0.f; acc[mt][nt][2] = 0.f; acc[mt][nt][3] = 0.f;
    }

  const int row0 = bx * 128 + w * 32 + l16;  // a0 row; a1 = row0+16
  const __hip_bfloat16* arow0b = nullptr;
  const __hip_bfloat16* arow1b = nullptr;
  const float* arow0f = nullptr;
  const float* arow1f = nullptr;
  bool isf32 = false;
  if constexpr (GATHER) {
    isf32 = flag[0] != 0;
    const int t0 = (dz ? t0b : t0f) + (row0 >> 6), b0 = row0 & 63;
    const int r1 = row0 + 16;
    const int t1 = (dz ? t0b : t0f) + (r1 >> 6), b1 = r1 & 63;
    const int tok0 = x[b0 * Tn + t0];
    const int tok1 = x[b1 * Tn + t1];
    if (isf32) {
      arow0f = (const float*)E + (size_t)tok0 * Dn;
      arow1f = (const float*)E + (size_t)tok1 * Dn;
    } else {
      arow0b = (const __hip_bfloat16*)E + (size_t)tok0 * Dn;
      arow1b = (const __hip_bfloat16*)E + (size_t)tok1 * Dn;
    }
  } else {
    const __hip_bfloat16* A = dz ? Ab : Af;
    arow0b = A + (size_t)row0 * K;
    arow1b = A + (size_t)(row0 + 16) * K;
  }

  for (int ch = 0; ch < K / KC; ++ch) {
    if (ch) __syncthreads();
    // stage B chunk: 128 cols x 256 shorts
#pragma unroll
    for (int it = 0; it < 16; ++it) {
      const int idx = it * 256 + tid;
      const int col = idx >> 5, seg = idx & 31;
      *(short8*)&Btile[col][seg * 8] =
          *(const short8*)(WTd + (size_t)(by * 128 + col) * K + ch * KC + seg * 8);
    }
    __syncthreads();

#pragma unroll
    for (int kc = 0; kc < 8; ++kc) {
      short8 a0, a1;
      if constexpr (GATHER) {
        if (isf32) {
#pragma unroll
          for (int jj = 0; jj < 8; ++jj) {
            __hip_bfloat16 h0 = __float2bfloat16(arow0f[kc * 32 + quad * 8 + jj]);
            __hip_bfloat16 h1 = __float2bfloat16(arow1f[kc * 32 + quad * 8 + jj]);
            a0[jj] = *(const short*)&h0;
            a1[jj] = *(const short*)&h1;
          }
        } else {
          a0 = *(const short8*)(arow0b + kc * 32 + quad * 8);
          a1 = *(const short8*)(arow1b + kc * 32 + quad * 8);
        }
      } else {
        a0 = *(const short8*)(arow0b + ch * KC + kc * 32 + quad * 8);
        a1 = *(const short8*)(arow1b + ch * KC + kc * 32 + quad * 8);
      }
#pragma unroll
      for (int nt = 0; nt < 8; ++nt) {
        const short8 b = *(const short8*)&Btile[nt * 16 + l16][kc * 32 + quad * 8];
        acc[0][nt] = __builtin_amdgcn_mfma_f32_16x16x32_bf16(a0, b, acc[0][nt], 0, 0, 0);
        acc[1][nt] = __builtin_amdgcn_mfma_f32_16x16x32_bf16(a1, b, acc[1][nt], 0, 0, 0);
      }
    }
  }

#pragma unroll
  for (int mt = 0; mt < 2; ++mt)
#pragma unroll
    for (int nt = 0; nt < 8; ++nt)
#pragma unroll
      for (int r = 0; r < 4; ++r)
        o[(size_t)(bx * 128 + w * 32 + mt * 16 + quad * 4 + r) * 1024 + by * 128 + nt * 16 +
          l16] = __float2bfloat16(acc[mt][nt][r]);
}

// ---------------------------------------------------------------------------
// Phased recurrent layer, TAGGED-PAYLOAD sync (r8/r9 validated, unchanged),
// now reading bf16 xproj and adding per-lane f32 biases (kept out of the
// quantized buffer -> forget-gate bias 1.0 stays exact).
// ---------------------------------------------------------------------------
template <bool WRITE_SEQ>
__launch_bounds__(256, 1) __global__
void k_lstm_fast(const __hip_bfloat16* __restrict__ WhT,   // [2][1024][256] this layer
                 const __hip_bfloat16* __restrict__ xproj,  // [2][Tc*64][1024] bf16
                 const float* __restrict__ biasL,           // [2][1024] this layer
                 const int* __restrict__ lengths,
                 unsigned* __restrict__ hgs,  // [2 d][2 par][4 q][64 b][64 u] u32
                 float* __restrict__ cstate, float* __restrict__ hstate,  // [2][64][256]
                 __hip_bfloat16* __restrict__ seq0,         // [T][64][512]
                 const int s0, const int Tc) {
  const int d = blockIdx.x >> 2;
  const int q = blockIdx.x & 3;
  const int tid = threadIdx.x;
  const int w = tid >> 6, L = tid & 63, quad = L >> 4, l16 = L & 15;
  const int u = q * 64 + w * 16 + l16;

  __shared__ __hip_bfloat16 h_lds[64][272];
  for (int idx = tid; idx < 64 * 272; idx += 256) (&h_lds[0][0])[idx] = __float2bfloat16(0.0f);

  const __hip_bfloat16* __restrict__ Wd = WhT + (size_t)d * (1024 * 256);
  short8 wfrag[4][8];
#pragma unroll
  for (int g = 0; g < 4; ++g)
#pragma unroll
    for (int kc = 0; kc < 8; ++kc)
      wfrag[g][kc] = *(const short8*)(Wd + (size_t)(g * 256 + u) * 256 + kc * 32 + quad * 8);

  float bz[4];
#pragma unroll
  for (int g = 0; g < 4; ++g) bz[g] = biasL[d * 1024 + g * 256 + u];

  float c_reg[16], h_reg[16];
  int len_b[16];
#pragma unroll
  for (int mt = 0; mt < 4; ++mt)
#pragma unroll
    for (int r = 0; r < 4; ++r) {
      const int idx = mt * 4 + r;
      const int b = mt * 16 + quad * 4 + r;
      len_b[idx] = lengths[b];
      if (s0 == 0) {
        c_reg[idx] = 0.0f;
        h_reg[idx] = 0.0f;
      } else {
        c_reg[idx] = cstate[((size_t)(d * 64 + b) << 8) + u];
        h_reg[idx] = hstate[((size_t)(d * 64 + b) << 8) + u];
      }
    }
  __syncthreads();
#pragma unroll
  for (int mt = 0; mt < 4; ++mt)
#pragma unroll
    for (int r = 0; r < 4; ++r)
      h_lds[mt * 16 + quad * 4 + r][u] = __float2bfloat16(h_reg[mt * 4 + r]);
  __syncthreads();

  for (int sl = 0; sl < Tc; ++sl) {
    const int s = s0 + sl;
    const int t = d ? (Tn - 1 - s) : s;
    const int tl = d ? (Tc - 1 - sl) : sl;

    // 1. C-init from bf16 xproj + f32 bias (issued before the exchange)
    f32x4 acc[4][4];
#pragma unroll
    for (int mt = 0; mt < 4; ++mt) {
      const __hip_bfloat16* __restrict__ xrow =
          xproj + ((size_t)(d * Tc + tl) * 64 + mt * 16 + quad * 4) * 1024 + u;
#pragma unroll
      for (int g = 0; g < 4; ++g)
#pragma unroll
        for (int r = 0; r < 4; ++r)
          acc[mt][g][r] = __bfloat162float(xrow[(size_t)r * 1024 + g * 256]) + bz[g];
    }

    // 2. tagged-payload exchange (single RT in the common case)
    if (s > 0) {
      if (w != q) {
        const unsigned long long* __restrict__ src64 =
            (const unsigned long long*)(hgs + ((((size_t)d * 2 + ((s - 1) & 1)) * 4 + w) << 12));
        const unsigned exp = (unsigned)s;
        unsigned long long v[32];
        unsigned pend = 0xFFFFFFFFu;
        int tries = 0;
        do {
          if (tries++) __builtin_amdgcn_s_sleep(1);
#pragma unroll
          for (int i = 0; i < 32; ++i)
            if (pend & (1u << i))
              v[i] = __hip_atomic_load(src64 + i * 64 + L, __ATOMIC_RELAXED,
                                       __HIP_MEMORY_SCOPE_AGENT);
#pragma unroll
          for (int i = 0; i < 32; ++i)
            if (pend & (1u << i)) {
              const unsigned lo = (unsigned)v[i], hi = (unsigned)(v[i] >> 32);
              if ((lo >> 16) == exp && (hi >> 16) == exp) pend &= ~(1u << i);
            }
        } while (pend);
#pragma unroll
        for (int i = 0; i < 32; ++i) {
          const int j = i * 64 + L;
          const unsigned lo = (unsigned)v[i], hi = (unsigned)(v[i] >> 32);
          const unsigned packed = (lo & 0xFFFFu) | (hi << 16);
          *(unsigned*)&h_lds[j >> 5][w * 64 + (j & 31) * 2] = packed;
        }
      }
      __syncthreads();
    }

    // 3. z += h @ Wh
#pragma unroll
    for (int kc = 0; kc < 8; ++kc) {
#pragma unroll
      for (int mt = 0; mt < 4; ++mt) {
        const short8 a = *(const short8*)&h_lds[mt * 16 + l16][kc * 32 + quad * 8];
#pragma unroll
        for (int g = 0; g < 4; ++g)
          acc[mt][g] =
              __builtin_amdgcn_mfma_f32_16x16x32_bf16(a, wfrag[g][kc], acc[mt][g], 0, 0, 0);
      }
    }

    // 4. gates + state update; publish tagged slice (write-through u32)
    unsigned* __restrict__ dst32 = hgs + ((((size_t)d * 2 + (s & 1)) * 4 + q) << 12);
    const unsigned tag = ((unsigned)(s + 1)) << 16;
    __hip_bfloat16 hbf[16];
#pragma unroll
    for (int mt = 0; mt < 4; ++mt)
#pragma unroll
      for (int r = 0; r < 4; ++r) {
        const int idx = mt * 4 + r, b = mt * 16 + quad * 4 + r;
        const float fg = sigmf(acc[mt][0][r]);
        const float ig = sigmf(acc[mt][1][r]);
        const float gg = tanh_fast(acc[mt][2][r]);
        const float og = sigmf(acc[mt][3][r]);
        const float cn = fg * c_reg[idx] + ig * gg;
        const float hn = og * tanh_fast(cn);
        if (t < len_b[idx]) {
          c_reg[idx] = cn;
          h_reg[idx] = hn;
        }
        hbf[idx] = __float2bfloat16(h_reg[idx]);
        __hip_atomic_store(dst32 + b * 64 + w * 16 + l16,
                           tag | (unsigned)*(unsigned short*)&hbf[idx], __ATOMIC_RELAXED,
                           __HIP_MEMORY_SCOPE_AGENT);
      }

    __syncthreads();  // LDS overwrite guard

#pragma unroll
    for (int mt = 0; mt < 4; ++mt)
#pragma unroll
      for (int r = 0; r < 4; ++r)
        h_lds[mt * 16 + quad * 4 + r][u] = hbf[mt * 4 + r];

    if (WRITE_SEQ) {
#pragma unroll
      for (int mt = 0; mt < 4; ++mt)
#pragma unroll
        for (int r = 0; r < 4; ++r) {
          const int b = mt * 16 + quad * 4 + r;
          seq0[((size_t)t * 64 + b) * 512 + d * 256 + u] = hbf[mt * 4 + r];
        }
    }
  }

#pragma unroll
  for (int mt = 0; mt < 4; ++mt)
#pragma unroll
    for (int r = 0; r < 4; ++r) {
      const int idx = mt * 4 + r, b = mt * 16 + quad * 4 + r;
      cstate[((size_t)(d * 64 + b) << 8) + u] = c_reg[idx];
      hstate[((size_t)(d * 64 + b) << 8) + u] = h_reg[idx];
    }
}

// ===========================================================================
// SLOW FALLBACK PATH (round-2 passing version, used when ws is too small)
// ===========================================================================
template <typename TW, int XK, bool WRITE_SEQ>
__device__ __forceinline__ void lstm_body(const int* __restrict__ x, const TW* __restrict__ E,
                                          const __hip_bfloat16* __restrict__ seq_in,
                                          const TW* __restrict__ W, const TW* __restrict__ bias,
                                          const int len, const int b, const int dir,
                                          __hip_bfloat16* __restrict__ seq_out,
                                          float* __restrict__ hfin) {
  const int j = threadIdx.x;
  __shared__ float h[Hn];
  __shared__ float xb[XK];
  float hj = 0.0f, cj = 0.0f;
  h[j] = 0.0f;
  const float bfj = ldf(bias, j);
  const float bij = ldf(bias, Hn + j);
  const float bgj = ldf(bias, 2 * Hn + j);
  const float boj = ldf(bias, 3 * Hn + j);
  __syncthreads();
  for (int s = 0; s < Tn; ++s) {
    const int t = dir ? (Tn - 1 - s) : s;
    const bool active = (t < len);
    if (active) {
      if constexpr (XK == Dn) {
        const int tok = x[b * Tn + t];
        xb[j] = ldf(E, (long)tok * Dn + j);
      } else {
        const long base = ((long)(b * Tn + t)) * (2 * Hn);
        xb[j] = __bfloat162float(seq_in[base + j]);
        xb[j + Hn] = __bfloat162float(seq_in[base + j + Hn]);
      }
      __syncthreads();
      float af = bfj, ai = bij, ag = bgj, ao = boj;
#pragma unroll 4
      for (int k = 0; k < Hn; ++k) {
        const float hk = h[k];
        const long r = (long)k * (4 * Hn);
        af += hk * ldf(W, r + j);
        ai += hk * ldf(W, r + Hn + j);
        ag += hk * ldf(W, r + 2 * Hn + j);
        ao += hk * ldf(W, r + 3 * Hn + j);
      }
#pragma unroll 4
      for (int k = 0; k < XK; ++k) {
        const float xk = xb[k];
        const long r = (long)(Hn + k) * (4 * Hn);
        af += xk * ldf(W, r + j);
        ai += xk * ldf(W, r + Hn + j);
        ag += xk * ldf(W, r + 2 * Hn + j);
        ao += xk * ldf(W, r + 3 * Hn + j);
      }
      const float fg = 1.0f / (1.0f + expf(-af));
      const float ig = 1.0f / (1.0f + expf(-ai));
      const float gg = tanhf(ag);
      const float og = 1.0f / (1.0f + expf(-ao));
      const float cn = fg * cj + ig * gg;
      const float hn = og * tanhf(cn);
      __syncthreads();
      hj = hn;
      cj = cn;
      h[j] = hn;
      __syncthreads();
    }
    if constexpr (WRITE_SEQ) {
      seq_out[((long)(b * Tn + t)) * (2 * Hn) + dir * Hn + j] = __float2bfloat16(hj);
    }
  }
  if constexpr (!WRITE_SEQ) hfin[(dir * Bn + b) * Hn + j] = hj;
}

template <int XK, bool WRITE_SEQ>
__global__ void k_lstm(const int* __restrict__ x, const void* __restrict__ E,
                       const __hip_bfloat16* __restrict__ seq_in, const void* __restrict__ Wf,
                       const void* __restrict__ bf, const void* __restrict__ Wb,
                       const void* __restrict__ bb, const int* __restrict__ lengths,
                       const int* __restrict__ flag, __hip_bfloat16* __restrict__ seq_out,
                       float* __restrict__ hfin) {
  const int b = blockIdx.x & (Bn - 1);
  const int dir = blockIdx.x >> 6;
  const int len = lengths[b];
  const void* W = dir ? Wb : Wf;
  const void* bias = dir ? bb : bf;
  if (flag[0]) {
    lstm_body<float, XK, WRITE_SEQ>(x, (const float*)E, seq_in, (const float*)W,
                                    (const float*)bias, len, b, dir, seq_out, hfin);
  } else {
    lstm_body<__hip_bfloat16, XK, WRITE_SEQ>(x, (const __hip_bfloat16*)E, seq_in,
                                             (const __hip_bfloat16*)W, (const __hip_bfloat16*)bias,
                                             len, b, dir, seq_out, hfin);
  }
}

// ---------------------------------------------------------------------------
template <typename TW>
__device__ __forceinline__ void fc_body(const float* __restrict__ hfin, const TW* __restrict__ Wfc,
                                        const TW* __restrict__ bfc, TW* __restrict__ out) {
  const int idx = threadIdx.x;
  const int b = idx >> 1;
  const int cc = idx & 1;
  float acc = ldf(bfc, cc);
  for (int k = 0; k < Hn; ++k) acc += hfin[(0 * Bn + b) * Hn + k] * ldf(Wfc, k * 2 + cc);
  for (int k = 0; k < Hn; ++k) acc += hfin[(1 * Bn + b) * Hn + k] * ldf(Wfc, (Hn + k) * 2 + cc);
  if constexpr (sizeof(TW) == 2) {
    out[b * 2 + cc] = __float2bfloat16(acc);
  } else {
    out[b * 2 + cc] = acc;
  }
}

__global__ void k_fc(const float* __restrict__ hfin, const void* __restrict__ Wfc,
                     const void* __restrict__ bfc, const int* __restrict__ flag,
                     void* __restrict__ out) {
  if (flag[0]) {
    fc_body<float>(hfin, (const float*)Wfc, (const float*)bfc, (float*)out);
  } else {
    fc_body<__hip_bfloat16>(hfin, (const __hip_bfloat16*)Wfc, (const __hip_bfloat16*)bfc,
                            (__hip_bfloat16*)out);
  }
}

// ---------------------------------------------------------------------------
extern "C" void kernel_launch(void* const* d_in, const int* in_sizes, int n_in,
                              void* d_out, int out_size, void* d_ws, size_t ws_size,
                              hipStream_t stream) {
  const int* x = (const int*)d_in[0];
  const void* E = d_in[1];
  const void* Wf0 = d_in[2];
  const void* bf0 = d_in[3];
  const void* Wb0 = d_in[4];
  const void* bb0 = d_in[5];
  const void* Wf1 = d_in[6];
  const void* bf1 = d_in[7];
  const void* Wb1 = d_in[8];
  const void* bb1 = d_in[9];
  const void* Wfc = d_in[10];
  const void* bfc = d_in[11];

  char* ws = (char*)d_ws;
  int* flag = (int*)ws;             // @0
  int* lengths = (int*)(ws + 256);

  const size_t MB = 1ull << 20;
  const size_t KB = 1024;

  k_detect<<<1, 256, 0, stream>>>((const unsigned short*)E, flag);
  k_lengths<<<Bn, 256, 0, stream>>>(x, lengths);

  // fixed 73 MB (weights/state/seq0) + one bf16 xproj slot Tc*256KB (reused L0/L1)
  int Tc = 0;
  {
    const size_t fixed = 73 * MB;
    const int cands[7] = {1024, 512, 256, 128, 64, 32, 16};
    for (int i = 0; i < 7; ++i)
      if (fixed + (size_t)cands[i] * 256 * KB <= ws_size) { Tc = cands[i]; break; }
  }

  if (Tc > 0) {
    float* biasbuf = (float*)(ws + 4096);                    // 16 KB
    __hip_bfloat16* whT = (__hip_bfloat16*)(ws + 1 * MB);    // [4][1024][256] = 2 MB
    __hip_bfloat16* wxT0 = (__hip_bfloat16*)(ws + 3 * MB);   // [2][1024][256] = 1 MB
    __hip_bfloat16* wxT1 = (__hip_bfloat16*)(ws + 4 * MB);   // [2][1024][512] = 2 MB
    unsigned* hgs0 = (unsigned*)(ws + 6 * MB);               // 256 KB
    unsigned* hgs1 = (unsigned*)(ws + 6 * MB + 256 * KB);    // 256 KB
    float* cstate0 = (float*)(ws + 7 * MB);                  // 128 KB
    float* hstate0 = (float*)(ws + 7 * MB + 128 * KB);       // 128 KB
    float* cstate1 = (float*)(ws + 7 * MB + 256 * KB);       // 128 KB
    float* hstate1 = (float*)(ws + 7 * MB + 384 * KB);       // 128 KB
    __hip_bfloat16* seq0 = (__hip_bfloat16*)(ws + 8 * MB);   // [1024][64][512] = 64 MB
    __hip_bfloat16* xsl = (__hip_bfloat16*)(ws + 73 * MB);   // [2][Tc*64][1024] bf16

    k_prep_small<<<1, 256, 0, stream>>>(bf0, bb0, bf1, bb1, flag, biasbuf);
    k_prepw<<<dim3(12, 16, 4), 256, 0, stream>>>(Wf0, Wb0, Wf1, Wb1, flag, whT, wxT0, wxT1);
    hipMemsetAsync(hgs0, 0, 512 * KB, stream);  // both mailboxes: kill stale tags

    const int P = Tn / Tc;
    const int Mrows = Tc * 64;
    const int ntiles = (Mrows / 128) * 16;
    // layer 0
    for (int p = 0; p < P; ++p) {
      const int s0 = p * Tc;
      const int t0f = s0, t0b = Tn - s0 - Tc;
      k_xproj3<256, true><<<ntiles, 256, 0, stream>>>(x, E, flag, nullptr, nullptr, wxT0, xsl,
                                                      Mrows, t0f, t0b);
      k_lstm_fast<true><<<8, 256, 0, stream>>>(whT, xsl, biasbuf, lengths, hgs0, cstate0, hstate0,
                                               seq0, s0, Tc);
    }
    // layer 1
    for (int p = 0; p < P; ++p) {
      const int s0 = p * Tc;
      const int t0f = s0, t0b = Tn - s0 - Tc;
      k_xproj3<512, false><<<ntiles, 256, 0, stream>>>(
          x, E, flag, seq0 + (size_t)t0f * 64 * 512, seq0 + (size_t)t0b * 64 * 512, wxT1, xsl,
          Mrows, 0, 0);
      k_lstm_fast<false><<<8, 256, 0, stream>>>(whT + 2 * 1024 * 256, xsl, biasbuf + 2048,
                                                lengths, hgs1, cstate1, hstate1, nullptr, s0, Tc);
    }
    k_fc<<<1, 128, 0, stream>>>(hstate1, Wfc, bfc, flag, d_out);
  } else {
    // slow fallback (round-2 passing path)
    __hip_bfloat16* seq0 = (__hip_bfloat16*)(ws + 64 * 1024);
    const size_t seq0_bytes = (size_t)Bn * Tn * 2 * Hn * sizeof(__hip_bfloat16);
    float* hfin = (float*)(ws + 64 * 1024 + seq0_bytes);
    k_lstm<Dn, true><<<2 * Bn, 256, 0, stream>>>(x, E, nullptr, Wf0, bf0, Wb0, bb0, lengths, flag,
                                                 seq0, nullptr);
    k_lstm<2 * Hn, false><<<2 * Bn, 256, 0, stream>>>(x, E, seq0, Wf1, bf1, Wb1, bb1, lengths,
                                                      flag, nullptr, hfin);
    k_fc<<<1, 128, 0, stream>>>(hfin, Wfc, bfc, flag, d_out);
  }
}